// Round 4
// baseline (249.135 us; speedup 1.0000x reference)
//
#include <hip/hip_runtime.h>
#include <math.h>

#define BB 4
#define CC 256
#define HH 64
#define WW 64
#define HW 4096
#define PH 68
#define PW 68
#define COUT 256
#define OFFC 216
#define KTOT 2304
#define NCHUNK 72

typedef __attribute__((ext_vector_type(4))) float f32x4;
typedef __attribute__((ext_vector_type(8))) short s16x8;
typedef __attribute__((ext_vector_type(8))) unsigned short u16x8;

__device__ __forceinline__ unsigned short f2bf(float f) {
    unsigned int u = __float_as_uint(f);
    return (unsigned short)((u + 0x7fffu + ((u >> 16) & 1u)) >> 16);
}
__device__ __forceinline__ float bf2f(unsigned short h) {
    return __uint_as_float(((unsigned int)h) << 16);
}

// ---------- pack main weight: wp[t][oc][kk], t=dg*9+tap, c=dg*32+kk
__global__ __launch_bounds__(256) void pack_w_main(const float* __restrict__ w,
                                                   unsigned short* __restrict__ wp) {
    int idx = blockIdx.x * 256 + threadIdx.x;
    int t = idx >> 13;
    int r = idx & 8191;
    int oc = r >> 5;
    int kk = r & 31;
    int dg = t / 9, tap = t % 9;
    int c = dg * 32 + kk;
    wp[idx] = f2bf(w[((size_t)oc * CC + c) * 9 + tap]);
}

// ---------- pack offset weight (pad 216->256 oc): t = tap*8+cg, c=cg*32+kk
__global__ __launch_bounds__(256) void pack_w_off(const float* __restrict__ w,
                                                  unsigned short* __restrict__ wp) {
    int idx = blockIdx.x * 256 + threadIdx.x;
    int t = idx >> 13;
    int r = idx & 8191;
    int oc = r >> 5;
    int kk = r & 31;
    int tap = t >> 3, cg = t & 7;
    int c = cg * 32 + kk;
    float v = (oc < OFFC) ? w[((size_t)oc * CC + c) * 9 + tap] : 0.f;
    wp[idx] = f2bf(v);
}

// ---------- NCHW f32 -> padded NHWC bf16 (zero ring of 2), LDS-transposed coalesced
__global__ __launch_bounds__(256) void pad_tr2(const float* __restrict__ srcx,
                                               const float* __restrict__ srce,
                                               unsigned short* __restrict__ dx_,
                                               unsigned short* __restrict__ de_) {
    const float* src = blockIdx.y ? srce : srcx;
    unsigned short* dst = blockIdx.y ? de_ : dx_;
    int blk = blockIdx.x;                 // b*PH + yp
    int b = blk / PH, yp = blk % PH;
    int y = yp - 2;
    unsigned short* drow = dst + ((size_t)b * PH + yp) * PW * CC;
    int tid = threadIdx.x;
    if ((unsigned)y >= (unsigned)HH) {    // zero ring row
        for (int i = tid; i < PW * CC / 8; i += 256) *(u16x8*)&drow[(size_t)i * 8] = (u16x8)0;
        return;
    }
    __shared__ float tile[64][65];
    int lane = tid & 63, w = tid >> 6;
    int oct = tid & 7, xi = tid >> 3;
    const float* srow = src + (size_t)b * CC * HW + (size_t)y * WW;
    for (int chunk = 0; chunk < 4; chunk++) {
        __syncthreads();
#pragma unroll
        for (int i = 0; i < 16; i++) {
            int c = chunk * 64 + w * 16 + i;
            tile[w * 16 + i][lane] = srow[(size_t)c * HW + lane];
        }
        __syncthreads();
#pragma unroll
        for (int xq = 0; xq < 3; xq++) {
            int xp = xq * 32 + xi;
            if (xp < PW) {
                int x = xp - 2;
                u16x8 v = (u16x8)0;
                if ((unsigned)x < (unsigned)WW) {
#pragma unroll
                    for (int e = 0; e < 8; e++) v[e] = f2bf(tile[oct * 8 + e][x]);
                }
                *(u16x8*)&drow[(size_t)xp * CC + chunk * 64 + oct * 8] = v;
            }
        }
    }
}

// ---------- offset conv: no LDS, no barriers. Wave = 128 oc x 16 px.
__global__ __launch_bounds__(256, 2) void off_mfma(const unsigned short* __restrict__ eT,
                                                   const unsigned short* __restrict__ wp,
                                                   const float* __restrict__ off_b,
                                                   float* __restrict__ om) {
    int blk = blockIdx.x;
    int b = blk >> 6, y = blk & 63;
    int ocbase = blockIdx.y * 128;
    int tid = threadIdx.x, lane = tid & 63;
    int r16 = lane & 15, lg = lane >> 4;
    int px = (tid >> 6) * 16 + r16;

    const unsigned short* eb = eT + (size_t)b * PH * PW * CC;

    f32x4 acc[8];
#pragma unroll
    for (int mi = 0; mi < 8; mi++) acc[mi] = (f32x4)0.f;
    s16x8 aA[8], aB[8], bA, bB;

#define O_B(T, BV)                                                                  \
    {                                                                               \
        int tap_ = (T) >> 3, cg_ = (T) & 7;                                         \
        int ky_ = tap_ / 3, kx_ = tap_ - ky_ * 3;                                   \
        BV = *(const s16x8*)&eb[((size_t)((y + ky_ + 1) * PW + (px + kx_ + 1))) * CC + \
                                cg_ * 32 + lg * 8];                                 \
    }
#define O_A(T, AF)                                                                  \
    {                                                                               \
        const unsigned short* wt_ = wp + (size_t)(T) * 8192 + (ocbase + r16) * 32 + lg * 8; \
        _Pragma("unroll") for (int mi = 0; mi < 8; mi++)                            \
            AF[mi] = *(const s16x8*)&wt_[mi * 512];                                 \
    }
#define O_IT(T, AC, AN, BC, BN)                                                     \
    {                                                                               \
        O_B((T) + 1, BN)                                                            \
        O_A((T) + 1, AN)                                                            \
        _Pragma("unroll") for (int mi = 0; mi < 8; mi++)                            \
            acc[mi] = __builtin_amdgcn_mfma_f32_16x16x32_bf16(AC[mi], BC, acc[mi], 0, 0, 0); \
    }

    O_B(0, bA)
    O_A(0, aA)
    for (int t = 0; t < NCHUNK; t += 2) {
        O_IT(t, aA, aB, bA, bB)
        O_IT(t + 1, aB, aA, bB, bA)
    }

#pragma unroll
    for (int mi = 0; mi < 8; mi++) {
#pragma unroll
        for (int j = 0; j < 4; j++) {
            int oc = ocbase + mi * 16 + lg * 4 + j;
            if (oc < OFFC)
                om[(size_t)(b * OFFC + oc) * HW + y * WW + px] = acc[mi][j] + off_b[oc];
        }
    }
}

// ---------- fused deformable sampling + main conv: no LDS, no barriers.
// Wave = 128 oc x 16 px. 2-deep pipeline: om(t+2) -> gathers(t+1) -> finish+MFMA(t).
__global__ __launch_bounds__(256, 2) void dconv_mfma(const unsigned short* __restrict__ xT,
                                                     const float* __restrict__ om,
                                                     const unsigned short* __restrict__ wp,
                                                     const float* __restrict__ bias,
                                                     float* __restrict__ out) {
    int blk = blockIdx.x;
    int b = blk >> 6, y = blk & 63;
    int ocbase = blockIdx.y * 128;
    int tid = threadIdx.x, lane = tid & 63;
    int r16 = lane & 15, lg = lane >> 4;
    int px = (tid >> 6) * 16 + r16;
    int yx = y * WW + px;

    const unsigned short* xb = xT + (size_t)b * PH * PW * CC;
    const float* omb = om + (size_t)b * OFFC * HW;

    f32x4 acc[8];
#pragma unroll
    for (int mi = 0; mi < 8; mi++) acc[mi] = (f32x4)0.f;
    s16x8 aA[8], aB[8];
    s16x8 cA00, cA01, cA10, cA11, cB00, cB01, cB10, cB11;
    float wA[4], wB[4];
    float omA0, omA1, omA2, omB0, omB1, omB2;

#define D_OM(T, D0, D1, D2)                                                          \
    {                                                                                \
        int dg_ = ((T) * 57) >> 9;                                                   \
        int tap_ = (T) - dg_ * 9;                                                    \
        D0 = omb[(size_t)(dg_ * 18 + 2 * tap_) * HW + yx];                           \
        D1 = omb[(size_t)(dg_ * 18 + 2 * tap_ + 1) * HW + yx];                       \
        D2 = omb[(size_t)(144 + dg_ * 9 + tap_) * HW + yx];                          \
    }
#define D_G(T, DY, DX, MR, C00, C01, C10, C11, W4)                                   \
    {                                                                                \
        int dg_ = ((T) * 57) >> 9;                                                   \
        int tap_ = (T) - dg_ * 9;                                                    \
        int ky_ = tap_ / 3, kx_ = tap_ - ky_ * 3;                                    \
        float mv_ = 1.f / (1.f + __expf(-(MR)));                                     \
        float py_ = (float)(y + ky_ - 1) + (DY);                                     \
        float pxx_ = (float)(px + kx_ - 1) + (DX);                                   \
        float y0f_ = floorf(py_), x0f_ = floorf(pxx_);                               \
        float fy_ = py_ - y0f_, fx_ = pxx_ - x0f_;                                   \
        int yp0_ = min(max((int)y0f_ + 2, 0), PH - 1);                               \
        int yp1_ = min(max((int)y0f_ + 3, 0), PH - 1);                               \
        int xp0_ = min(max((int)x0f_ + 2, 0), PW - 1);                               \
        int xp1_ = min(max((int)x0f_ + 3, 0), PW - 1);                               \
        const unsigned short* cbp_ = xb + dg_ * 32 + lg * 8;                         \
        C00 = *(const s16x8*)&cbp_[(size_t)(yp0_ * PW + xp0_) * CC];                 \
        C01 = *(const s16x8*)&cbp_[(size_t)(yp0_ * PW + xp1_) * CC];                 \
        C10 = *(const s16x8*)&cbp_[(size_t)(yp1_ * PW + xp0_) * CC];                 \
        C11 = *(const s16x8*)&cbp_[(size_t)(yp1_ * PW + xp1_) * CC];                 \
        W4[0] = (1.f - fy_) * (1.f - fx_) * mv_;                                     \
        W4[1] = (1.f - fy_) * fx_ * mv_;                                             \
        W4[2] = fy_ * (1.f - fx_) * mv_;                                             \
        W4[3] = fy_ * fx_ * mv_;                                                     \
    }
#define D_A(T, AF)                                                                   \
    {                                                                                \
        const unsigned short* wt_ = wp + (size_t)(T) * 8192 + (ocbase + r16) * 32 + lg * 8; \
        _Pragma("unroll") for (int mi = 0; mi < 8; mi++)                             \
            AF[mi] = *(const s16x8*)&wt_[mi * 512];                                  \
    }
#define D_FIN(C00, C01, C10, C11, W4, BV)                                            \
    {                                                                                \
        _Pragma("unroll") for (int j = 0; j < 8; j++) {                              \
            float v_ = W4[0] * bf2f((unsigned short)C00[j]);                         \
            v_ = fmaf(W4[1], bf2f((unsigned short)C01[j]), v_);                      \
            v_ = fmaf(W4[2], bf2f((unsigned short)C10[j]), v_);                      \
            v_ = fmaf(W4[3], bf2f((unsigned short)C11[j]), v_);                      \
            BV[j] = (short)f2bf(v_);                                                 \
        }                                                                            \
    }
#define D_IT(T, AC, AN, C0C, C1C, C2C, C3C, WC, C0N, C1N, C2N, C3N, WN, OC0, OC1, OC2, ON0, ON1, ON2) \
    {                                                                                \
        D_OM((T) + 2, ON0, ON1, ON2)                                                 \
        D_G((T) + 1, OC0, OC1, OC2, C0N, C1N, C2N, C3N, WN)                          \
        D_A((T) + 1, AN)                                                             \
        s16x8 bv_;                                                                   \
        D_FIN(C0C, C1C, C2C, C3C, WC, bv_)                                           \
        _Pragma("unroll") for (int mi = 0; mi < 8; mi++)                             \
            acc[mi] = __builtin_amdgcn_mfma_f32_16x16x32_bf16(AC[mi], bv_, acc[mi], 0, 0, 0); \
    }

    // prologue: om(0)->gather(0); A(0); om(1) in flight
    {
        float d0, d1, d2;
        D_OM(0, d0, d1, d2)
        D_G(0, d0, d1, d2, cA00, cA01, cA10, cA11, wA)
    }
    D_A(0, aA)
    D_OM(1, omA0, omA1, omA2)

    for (int t = 0; t < NCHUNK; t += 2) {
        D_IT(t, aA, aB, cA00, cA01, cA10, cA11, wA, cB00, cB01, cB10, cB11, wB,
             omA0, omA1, omA2, omB0, omB1, omB2)
        D_IT(t + 1, aB, aA, cB00, cB01, cB10, cB11, wB, cA00, cA01, cA10, cA11, wA,
             omB0, omB1, omB2, omA0, omA1, omA2)
    }

#pragma unroll
    for (int mi = 0; mi < 8; mi++) {
#pragma unroll
        for (int j = 0; j < 4; j++) {
            int oc = ocbase + mi * 16 + lg * 4 + j;
            out[(size_t)(b * COUT + oc) * HW + y * WW + px] = acc[mi][j] + bias[oc];
        }
    }
}

extern "C" void kernel_launch(void* const* d_in, const int* in_sizes, int n_in,
                              void* d_out, int out_size, void* d_ws, size_t ws_size,
                              hipStream_t stream) {
    const float* x = (const float*)d_in[0];
    const float* extra_feat = (const float*)d_in[1];
    const float* weight = (const float*)d_in[2];
    const float* bias = (const float*)d_in[3];
    const float* off_w = (const float*)d_in[4];
    const float* off_b = (const float*)d_in[5];
    float* out = (float*)d_out;

    // workspace layout
    float* om = (float*)d_ws;                                       // 4*216*4096 f32
    unsigned short* wpm = (unsigned short*)(om + (size_t)BB * OFFC * HW);
    unsigned short* wpo = wpm + (size_t)KTOT * COUT;                // 2304*256 bf16
    unsigned short* xT = wpo + (size_t)KTOT * COUT;                 // 4*68*68*256 bf16
    unsigned short* eT = xT + (size_t)BB * PH * PW * CC;            // 4*68*68*256 bf16

    pack_w_main<<<(KTOT * COUT) / 256, 256, 0, stream>>>(weight, wpm);
    pack_w_off<<<(KTOT * COUT) / 256, 256, 0, stream>>>(off_w, wpo);
    pad_tr2<<<dim3(BB * PH, 2), 256, 0, stream>>>(x, extra_feat, xT, eT);

    off_mfma<<<dim3(BB * HH, 2), 256, 0, stream>>>(eT, wpo, off_b, om);
    dconv_mfma<<<dim3(BB * HH, 2), 256, 0, stream>>>(xT, om, wpm, bias, out);
}

// Round 5
// 192.209 us; speedup vs baseline: 1.2962x; 1.2962x over previous
//
#include <hip/hip_runtime.h>
#include <math.h>

#define BB 4
#define CC 256
#define HH 64
#define WW 64
#define HW 4096
#define PH 68
#define PW 68
#define COUT 256
#define OFFC 216
#define KTOT 2304
#define NCHUNK 72

typedef __attribute__((ext_vector_type(4))) float f32x4;
typedef __attribute__((ext_vector_type(8))) short s16x8;
typedef __attribute__((ext_vector_type(4))) short s16x4;
typedef __attribute__((ext_vector_type(8))) unsigned short u16x8;

__device__ __forceinline__ unsigned short f2bf(float f) {
    unsigned int u = __float_as_uint(f);
    return (unsigned short)((u + 0x7fffu + ((u >> 16) & 1u)) >> 16);
}
__device__ __forceinline__ float bf2f(unsigned short h) {
    return __uint_as_float(((unsigned int)h) << 16);
}

// ---------- pack main weight: wp[t][oc][kk], t=dg*9+tap, c=dg*32+kk
__global__ __launch_bounds__(256) void pack_w_main(const float* __restrict__ w,
                                                   unsigned short* __restrict__ wp) {
    int idx = blockIdx.x * 256 + threadIdx.x;
    int t = idx >> 13;
    int r = idx & 8191;
    int oc = r >> 5;
    int kk = r & 31;
    int dg = t / 9, tap = t % 9;
    int c = dg * 32 + kk;
    wp[idx] = f2bf(w[((size_t)oc * CC + c) * 9 + tap]);
}

// ---------- pack offset weight (pad 216->256 oc): t = tap*8+cg, c=cg*32+kk
__global__ __launch_bounds__(256) void pack_w_off(const float* __restrict__ w,
                                                  unsigned short* __restrict__ wp) {
    int idx = blockIdx.x * 256 + threadIdx.x;
    int t = idx >> 13;
    int r = idx & 8191;
    int oc = r >> 5;
    int kk = r & 31;
    int tap = t >> 3, cg = t & 7;
    int c = cg * 32 + kk;
    float v = (oc < OFFC) ? w[((size_t)oc * CC + c) * 9 + kk % 1 + 0 * kk] : 0.f; // placeholder to keep structure clear
    v = (oc < OFFC) ? w[((size_t)oc * CC + c) * 9 + tap] : 0.f;
    wp[idx] = f2bf(v);
}

// ---------- NCHW f32 -> padded NHWC bf16 (zero ring of 2), LDS-transposed coalesced
__global__ __launch_bounds__(256) void pad_tr2(const float* __restrict__ srcx,
                                               const float* __restrict__ srce,
                                               unsigned short* __restrict__ dx_,
                                               unsigned short* __restrict__ de_) {
    const float* src = blockIdx.y ? srce : srcx;
    unsigned short* dst = blockIdx.y ? de_ : dx_;
    int blk = blockIdx.x;                 // b*PH + yp
    int b = blk / PH, yp = blk % PH;
    int y = yp - 2;
    unsigned short* drow = dst + ((size_t)b * PH + yp) * PW * CC;
    int tid = threadIdx.x;
    if ((unsigned)y >= (unsigned)HH) {    // zero ring row
        for (int i = tid; i < PW * CC / 8; i += 256) *(u16x8*)&drow[(size_t)i * 8] = (u16x8)0;
        return;
    }
    __shared__ float tile[64][65];
    int lane = tid & 63, w = tid >> 6;
    int oct = tid & 7, xi = tid >> 3;
    const float* srow = src + (size_t)b * CC * HW + (size_t)y * WW;
    for (int chunk = 0; chunk < 4; chunk++) {
        __syncthreads();
#pragma unroll
        for (int i = 0; i < 16; i++) {
            int c = chunk * 64 + w * 16 + i;
            tile[w * 16 + i][lane] = srow[(size_t)c * HW + lane];
        }
        __syncthreads();
#pragma unroll
        for (int xq = 0; xq < 3; xq++) {
            int xp = xq * 32 + xi;
            if (xp < PW) {
                int x = xp - 2;
                u16x8 v = (u16x8)0;
                if ((unsigned)x < (unsigned)WW) {
#pragma unroll
                    for (int e = 0; e < 8; e++) v[e] = f2bf(tile[oct * 8 + e][x]);
                }
                *(u16x8*)&drow[(size_t)xp * CC + chunk * 64 + oct * 8] = v;
            }
        }
    }
}

// ======================================================================
// offset conv: block = 256 oc x 32 px, grid (256 rows, 2 px-halves).
// A: per-wave 64oc frags from L2 (prefetch 1 ahead). B: LDS dbuf, 1 barrier/iter.
// Epilogue writes interleaved om4[b][t][px][{dy,dx,mraw,pad}].
// ======================================================================
__global__ __launch_bounds__(256, 2) void off_mfma(const unsigned short* __restrict__ eT,
                                                   const unsigned short* __restrict__ wp,
                                                   const float* __restrict__ off_b,
                                                   float* __restrict__ om4) {
    __shared__ unsigned short sB[2][4 * 32 * 8];   // [buf][ko*32+px][8ch]
    int blk = blockIdx.x;
    int b = blk >> 6, y = blk & 63;
    int pxh = blockIdx.y;
    int tid = threadIdx.x, lane = tid & 63, wid = tid >> 6;
    int r16 = lane & 15, lg = lane >> 4;
    int pxs = tid & 31, q = tid >> 5;   // q 0..7: ko=q>>1, half=q&1
    int pxg = pxh * 32 + pxs;
    int wslot = ((q >> 1) * 32 + pxs) * 8 + (q & 1) * 4;

    const unsigned short* eb = eT + (size_t)b * PH * PW * CC;

    f32x4 acc[4][2];
#pragma unroll
    for (int mi = 0; mi < 4; mi++)
#pragma unroll
        for (int ni = 0; ni < 2; ni++) acc[mi][ni] = (f32x4)0.f;

    s16x8 aA[4], aB[4];

#define OF_SV(T, SV)                                                              \
    {                                                                             \
        int tap_ = (T) >> 3, cg_ = (T) & 7;                                       \
        int ky_ = tap_ / 3, kx_ = tap_ - ky_ * 3;                                 \
        SV = *(const s16x4*)&eb[((size_t)((y + ky_ + 1) * PW + (pxg + kx_ + 1))) * CC + \
                                cg_ * 32 + q * 4];                                \
    }
#define OF_A(T, AF)                                                               \
    {                                                                             \
        const unsigned short* wt_ = wp + (size_t)(T) * 8192 + (wid * 64 + r16) * 32 + lg * 8; \
        _Pragma("unroll") for (int mi = 0; mi < 4; mi++)                          \
            AF[mi] = *(const s16x8*)&wt_[mi * 512];                               \
    }
#define OF_IT(T, AC, AN, BUF)                                                     \
    {                                                                             \
        __syncthreads();                                                          \
        s16x4 sv_;                                                                \
        if ((T) + 1 < NCHUNK) {                                                   \
            OF_SV((T) + 1, sv_)                                                   \
            OF_A((T) + 1, AN)                                                     \
        }                                                                         \
        s16x8 bfv[2];                                                             \
        _Pragma("unroll") for (int ni = 0; ni < 2; ni++)                          \
            bfv[ni] = *(const s16x8*)&sB[BUF][(lg * 32 + ni * 16 + r16) * 8];     \
        _Pragma("unroll") for (int mi = 0; mi < 4; mi++)                          \
        _Pragma("unroll") for (int ni = 0; ni < 2; ni++)                          \
            acc[mi][ni] = __builtin_amdgcn_mfma_f32_16x16x32_bf16(                \
                AC[mi], bfv[ni], acc[mi][ni], 0, 0, 0);                           \
        if ((T) + 1 < NCHUNK) *(s16x4*)&sB[(BUF) ^ 1][wslot] = sv_;               \
    }

    // prologue: B(0) -> LDS, A(0) -> regs
    {
        s16x4 sv0;
        OF_SV(0, sv0)
        *(s16x4*)&sB[0][wslot] = sv0;
        OF_A(0, aA)
    }
    for (int t = 0; t < NCHUNK; t += 2) {
        OF_IT(t, aA, aB, 0)
        OF_IT(t + 1, aB, aA, 1)
    }

    // epilogue: scatter into interleaved om4
    float* omb4 = om4 + (size_t)b * NCHUNK * HW * 4;
#pragma unroll
    for (int mi = 0; mi < 4; mi++) {
#pragma unroll
        for (int ni = 0; ni < 2; ni++) {
#pragma unroll
            for (int j = 0; j < 4; j++) {
                int oc = wid * 64 + mi * 16 + lg * 4 + j;
                if (oc < OFFC) {
                    int pxo = pxh * 32 + ni * 16 + r16;
                    float v = acc[mi][ni][j] + off_b[oc];
                    int dg, tap, comp;
                    if (oc < 144) {
                        dg = oc / 18;
                        int r = oc - dg * 18;
                        tap = r >> 1;
                        comp = r & 1;
                    } else {
                        int o2 = oc - 144;
                        dg = o2 / 9;
                        tap = o2 - dg * 9;
                        comp = 2;
                    }
                    omb4[((size_t)(dg * 9 + tap) * HW + y * WW + pxo) * 4 + comp] = v;
                }
            }
        }
    }
}

// ======================================================================
// fused deformable sampling + main conv, same skeleton.
// ======================================================================
__global__ __launch_bounds__(256, 2) void dconv_mfma(const unsigned short* __restrict__ xT,
                                                     const float* __restrict__ om4,
                                                     const unsigned short* __restrict__ wp,
                                                     const float* __restrict__ bias,
                                                     float* __restrict__ out) {
    __shared__ unsigned short sB[2][4 * 32 * 8];
    int blk = blockIdx.x;
    int b = blk >> 6, y = blk & 63;
    int pxh = blockIdx.y;
    int tid = threadIdx.x, lane = tid & 63, wid = tid >> 6;
    int r16 = lane & 15, lg = lane >> 4;
    int pxs = tid & 31, q = tid >> 5;
    int pxg = pxh * 32 + pxs;
    int wslot = ((q >> 1) * 32 + pxs) * 8 + (q & 1) * 4;

    const unsigned short* xb = xT + (size_t)b * PH * PW * CC;
    const float* omb4 = om4 + (size_t)b * NCHUNK * HW * 4;

    f32x4 acc[4][2];
#pragma unroll
    for (int mi = 0; mi < 4; mi++)
#pragma unroll
        for (int ni = 0; ni < 2; ni++) acc[mi][ni] = (f32x4)0.f;

    s16x8 aA[4], aB[4];
    f32x4 omA = (f32x4)0.f, omB = (f32x4)0.f;

#define DC_OM(T, OV) { OV = *(const f32x4*)&omb4[((size_t)(T)*HW + y * WW + pxg) * 4]; }
#define DC_A(T, AF)                                                               \
    {                                                                             \
        const unsigned short* wt_ = wp + (size_t)(T) * 8192 + (wid * 64 + r16) * 32 + lg * 8; \
        _Pragma("unroll") for (int mi = 0; mi < 4; mi++)                          \
            AF[mi] = *(const s16x8*)&wt_[mi * 512];                               \
    }
    // compute position from OV, issue 4 corner gathers (4 channels each)
#define DC_G(T, OV, C00, C01, C10, C11, W0, W1, W2, W3)                           \
    {                                                                             \
        int dg_ = ((T) * 57) >> 9;                                                \
        int tap_ = (T) - dg_ * 9;                                                 \
        int ky_ = tap_ / 3, kx_ = tap_ - ky_ * 3;                                 \
        float mv_ = 1.f / (1.f + __expf(-OV[2]));                                 \
        float py_ = (float)(y + ky_ - 1) + OV[0];                                 \
        float pxx_ = (float)(pxg + kx_ - 1) + OV[1];                              \
        float y0f_ = floorf(py_), x0f_ = floorf(pxx_);                            \
        float fy_ = py_ - y0f_, fx_ = pxx_ - x0f_;                                \
        int yp0_ = min(max((int)y0f_ + 2, 0), PH - 1);                            \
        int yp1_ = min(max((int)y0f_ + 3, 0), PH - 1);                            \
        int xp0_ = min(max((int)x0f_ + 2, 0), PW - 1);                            \
        int xp1_ = min(max((int)x0f_ + 3, 0), PW - 1);                            \
        const unsigned short* cb_ = xb + dg_ * 32 + q * 4;                        \
        C00 = *(const s16x4*)&cb_[(size_t)(yp0_ * PW + xp0_) * CC];               \
        C01 = *(const s16x4*)&cb_[(size_t)(yp0_ * PW + xp1_) * CC];               \
        C10 = *(const s16x4*)&cb_[(size_t)(yp1_ * PW + xp0_) * CC];               \
        C11 = *(const s16x4*)&cb_[(size_t)(yp1_ * PW + xp1_) * CC];               \
        W0 = (1.f - fy_) * (1.f - fx_) * mv_;                                     \
        W1 = (1.f - fy_) * fx_ * mv_;                                             \
        W2 = fy_ * (1.f - fx_) * mv_;                                             \
        W3 = fy_ * fx_ * mv_;                                                     \
    }
#define DC_FIN(C00, C01, C10, C11, W0, W1, W2, W3, BUF)                           \
    {                                                                             \
        s16x4 bv_;                                                                \
        _Pragma("unroll") for (int e = 0; e < 4; e++) {                           \
            float v_ = W0 * bf2f((unsigned short)C00[e]);                         \
            v_ = fmaf(W1, bf2f((unsigned short)C01[e]), v_);                      \
            v_ = fmaf(W2, bf2f((unsigned short)C10[e]), v_);                      \
            v_ = fmaf(W3, bf2f((unsigned short)C11[e]), v_);                      \
            bv_[e] = (short)f2bf(v_);                                             \
        }                                                                         \
        *(s16x4*)&sB[BUF][wslot] = bv_;                                           \
    }
#define DC_IT(T, AC, AN, OC, ON, BUF)                                             \
    {                                                                             \
        __syncthreads();                                                          \
        s16x4 c00_, c01_, c10_, c11_;                                             \
        float w0_ = 0.f, w1_ = 0.f, w2_ = 0.f, w3_ = 0.f;                         \
        if ((T) + 1 < NCHUNK) {                                                   \
            DC_G((T) + 1, OC, c00_, c01_, c10_, c11_, w0_, w1_, w2_, w3_)         \
            DC_A((T) + 1, AN)                                                     \
        }                                                                         \
        if ((T) + 2 < NCHUNK) DC_OM((T) + 2, ON)                                  \
        s16x8 bfv[2];                                                             \
        _Pragma("unroll") for (int ni = 0; ni < 2; ni++)                          \
            bfv[ni] = *(const s16x8*)&sB[BUF][(lg * 32 + ni * 16 + r16) * 8];     \
        _Pragma("unroll") for (int mi = 0; mi < 4; mi++)                          \
        _Pragma("unroll") for (int ni = 0; ni < 2; ni++)                          \
            acc[mi][ni] = __builtin_amdgcn_mfma_f32_16x16x32_bf16(                \
                AC[mi], bfv[ni], acc[mi][ni], 0, 0, 0);                           \
        if ((T) + 1 < NCHUNK) DC_FIN(c00_, c01_, c10_, c11_, w0_, w1_, w2_, w3_, (BUF) ^ 1) \
    }

    // prologue: B(0) staged, A(0) loaded, om(1) in flight
    {
        f32x4 om0;
        DC_OM(0, om0)
        s16x4 c00_, c01_, c10_, c11_;
        float w0_, w1_, w2_, w3_;
        DC_G(0, om0, c00_, c01_, c10_, c11_, w0_, w1_, w2_, w3_)
        DC_A(0, aA)
        DC_OM(1, omA)
        DC_FIN(c00_, c01_, c10_, c11_, w0_, w1_, w2_, w3_, 0)
    }
    for (int t = 0; t < NCHUNK; t += 2) {
        DC_IT(t, aA, aB, omA, omB, 0)
        DC_IT(t + 1, aB, aA, omB, omA, 1)
    }

#pragma unroll
    for (int mi = 0; mi < 4; mi++) {
#pragma unroll
        for (int ni = 0; ni < 2; ni++) {
#pragma unroll
            for (int j = 0; j < 4; j++) {
                int oc = wid * 64 + mi * 16 + lg * 4 + j;
                int pxo = pxh * 32 + ni * 16 + r16;
                out[(size_t)(b * COUT + oc) * HW + y * WW + pxo] = acc[mi][ni][j] + bias[oc];
            }
        }
    }
}

extern "C" void kernel_launch(void* const* d_in, const int* in_sizes, int n_in,
                              void* d_out, int out_size, void* d_ws, size_t ws_size,
                              hipStream_t stream) {
    const float* x = (const float*)d_in[0];
    const float* extra_feat = (const float*)d_in[1];
    const float* weight = (const float*)d_in[2];
    const float* bias = (const float*)d_in[3];
    const float* off_w = (const float*)d_in[4];
    const float* off_b = (const float*)d_in[5];
    float* out = (float*)d_out;

    // workspace layout
    float* om4 = (float*)d_ws;                                      // 4*72*4096*4 f32 (18.9 MB)
    unsigned short* wpm = (unsigned short*)(om4 + (size_t)BB * NCHUNK * HW * 4);
    unsigned short* wpo = wpm + (size_t)KTOT * COUT;                // 1.18 MB each
    unsigned short* xT = wpo + (size_t)KTOT * COUT;                 // 9.05 MB
    unsigned short* eT = xT + (size_t)BB * PH * PW * CC;            // 9.05 MB

    pack_w_main<<<(KTOT * COUT) / 256, 256, 0, stream>>>(weight, wpm);
    pack_w_off<<<(KTOT * COUT) / 256, 256, 0, stream>>>(off_w, wpo);
    pad_tr2<<<dim3(BB * PH, 2), 256, 0, stream>>>(x, extra_feat, xT, eT);

    off_mfma<<<dim3(BB * HH, 2), 256, 0, stream>>>(eT, wpo, off_b, om4);
    dconv_mfma<<<dim3(BB * HH, 2), 256, 0, stream>>>(xT, om4, wpm, bias, out);
}

// Round 6
// 143.807 us; speedup vs baseline: 1.7324x; 1.3366x over previous
//
#include <hip/hip_runtime.h>
#include <hip/hip_bf16.h>
#include <math.h>

#define BB 4
#define CC 256
#define HH 64
#define WW 64
#define HW 4096
#define PH 68
#define PW 68
#define COUT 256
#define OFFC 216
#define KTOT 2304
#define NCHUNK 72

typedef __attribute__((ext_vector_type(4))) float f32x4;
typedef __attribute__((ext_vector_type(8))) short s16x8;
typedef __attribute__((ext_vector_type(8))) unsigned short u16x8;
typedef __attribute__((ext_vector_type(2))) unsigned int u32x2;
typedef __attribute__((ext_vector_type(4))) unsigned int u32x4;

__device__ __forceinline__ unsigned short f2bf(float f) {
    unsigned int u = __float_as_uint(f);
    return (unsigned short)((u + 0x7fffu + ((u >> 16) & 1u)) >> 16);
}
__device__ __forceinline__ float bflo(unsigned int u) { return __uint_as_float(u << 16); }
__device__ __forceinline__ float bfhi(unsigned int u) { return __uint_as_float(u & 0xffff0000u); }
__device__ __forceinline__ unsigned int pkbf(float a, float b) {
    __hip_bfloat162 h = __float22bfloat162_rn(make_float2(a, b));
    unsigned int r;
    __builtin_memcpy(&r, &h, 4);
    return r;
}
__device__ __forceinline__ void glds16(const void* g, void* l) {
    __builtin_amdgcn_global_load_lds((const __attribute__((address_space(1))) unsigned int*)g,
                                     (__attribute__((address_space(3))) unsigned int*)l, 16, 0, 0);
}

// ---------- pack main weight, bank-swizzled rows of 64B:
// tile t (=dg*9+tap, 8192 elems): elem (oc, slot, e) holds kk = ((slot ^ ((oc>>1)&3))<<3)|e, c = dg*32+kk
__global__ __launch_bounds__(256) void pack_w_main(const float* __restrict__ w,
                                                   unsigned short* __restrict__ wp) {
    int idx = blockIdx.x * 256 + threadIdx.x;
    int t = idx >> 13, r = idx & 8191;
    int oc = r >> 5, slot = (r >> 3) & 3, e = r & 7;
    int kk = ((slot ^ ((oc >> 1) & 3)) << 3) | e;
    int dg = t / 9, tap = t - dg * 9;
    int c = dg * 32 + kk;
    wp[idx] = f2bf(w[((size_t)oc * CC + c) * 9 + tap]);
}

// ---------- pack offset weight (pad 216->256), t = tap*8+cg, same swizzle
__global__ __launch_bounds__(256) void pack_w_off(const float* __restrict__ w,
                                                  unsigned short* __restrict__ wp) {
    int idx = blockIdx.x * 256 + threadIdx.x;
    int t = idx >> 13, r = idx & 8191;
    int oc = r >> 5, slot = (r >> 3) & 3, e = r & 7;
    int kk = ((slot ^ ((oc >> 1) & 3)) << 3) | e;
    int tap = t >> 3, cg = t & 7;
    int c = cg * 32 + kk;
    float v = (oc < OFFC) ? w[((size_t)oc * CC + c) * 9 + tap] : 0.f;
    wp[idx] = f2bf(v);
}

// ---------- NCHW f32 -> padded NHWC bf16 (zero ring of 2), LDS-transposed coalesced
__global__ __launch_bounds__(256) void pad_tr2(const float* __restrict__ srcx,
                                               const float* __restrict__ srce,
                                               unsigned short* __restrict__ dx_,
                                               unsigned short* __restrict__ de_) {
    const float* src = blockIdx.y ? srce : srcx;
    unsigned short* dst = blockIdx.y ? de_ : dx_;
    int blk = blockIdx.x;
    int b = blk / PH, yp = blk % PH;
    int y = yp - 2;
    unsigned short* drow = dst + ((size_t)b * PH + yp) * PW * CC;
    int tid = threadIdx.x;
    if ((unsigned)y >= (unsigned)HH) {
        for (int i = tid; i < PW * CC / 8; i += 256) *(u16x8*)&drow[(size_t)i * 8] = (u16x8)0;
        return;
    }
    __shared__ float tile[64][65];
    int lane = tid & 63, w = tid >> 6;
    int oct = tid & 7, xi = tid >> 3;
    const float* srow = src + (size_t)b * CC * HW + (size_t)y * WW;
    for (int chunk = 0; chunk < 4; chunk++) {
        __syncthreads();
#pragma unroll
        for (int i = 0; i < 16; i++) {
            int c = chunk * 64 + w * 16 + i;
            tile[w * 16 + i][lane] = srow[(size_t)c * HW + lane];
        }
        __syncthreads();
#pragma unroll
        for (int xq = 0; xq < 3; xq++) {
            int xp = xq * 32 + xi;
            if (xp < PW) {
                int x = xp - 2;
                u16x8 v = (u16x8)0;
                if ((unsigned)x < (unsigned)WW) {
#pragma unroll
                    for (int e = 0; e < 8; e++) v[e] = f2bf(tile[oct * 8 + e][x]);
                }
                *(u16x8*)&drow[(size_t)xp * CC + chunk * 64 + oct * 8] = v;
            }
        }
    }
}

// ---------- prep: raw {dy,dx,mraw,·} -> {packed idx, bf16 w00|w01, w10|w11, 0}, IN PLACE
__global__ __launch_bounds__(256) void prep_off(float* __restrict__ om) {
    int idx = blockIdx.x * 256 + threadIdx.x;
    const int per_b = NCHUNK * HW;
    int b = idx / per_b;
    int r = idx - b * per_b;
    int t = r >> 12, p = r & 4095;
    int y = p >> 6, x = p & 63;
    f32x4 raw = *((const f32x4*)om + idx);
    int dg = (t * 57) >> 9;
    int tap = t - dg * 9;
    int ky = tap / 3, kx = tap - ky * 3;
    float mv = 1.f / (1.f + __expf(-raw[2]));
    float py = (float)(y + ky - 1) + raw[0];
    float px = (float)(x + kx - 1) + raw[1];
    float y0f = floorf(py), x0f = floorf(px);
    float fy = py - y0f, fx = px - x0f;
    int yp0 = min(max((int)y0f + 2, 0), PH - 1);
    int yp1 = min(max((int)y0f + 3, 0), PH - 1);
    int xp0 = min(max((int)x0f + 2, 0), PW - 1);
    int xp1 = min(max((int)x0f + 3, 0), PW - 1);
    unsigned int iv = (unsigned int)(yp0 * PW + xp0) | ((unsigned int)(xp1 - xp0) << 13) |
                      ((unsigned int)(yp1 - yp0) << 14);
    float w00 = (1.f - fy) * (1.f - fx) * mv;
    float w01 = (1.f - fy) * fx * mv;
    float w10 = fy * (1.f - fx) * mv;
    float w11 = fy * fx * mv;
    u32x4 o;
    o[0] = iv;
    o[1] = pkbf(w00, w01);
    o[2] = pkbf(w10, w11);
    o[3] = 0;
    *((u32x4*)om + idx) = o;
}

// shared GEMM pieces: block = 128oc x 64px, 8 waves (wm 0..3 x wn 0..1), wave = 32oc x 32px
#define GLDSA(WPP, T, BUF) \
    glds16(WPP + (size_t)(T) * 8192 + ocbase * 32 + tid * 8, &sA[BUF][wu * 1024])

#define MFMA4(BUF)                                                                         \
    {                                                                                      \
        s16x8 a0 = *(const s16x8*)&sA[BUF][(wm * 32 + r16) * 64 + ((lg ^ swz) << 4)];      \
        s16x8 a1 = *(const s16x8*)&sA[BUF][(wm * 32 + 16 + r16) * 64 + ((lg ^ swz) << 4)]; \
        s16x8 b0 = *(const s16x8*)&sB[BUF][wn * 32 + r16][lg * 8];                         \
        s16x8 b1 = *(const s16x8*)&sB[BUF][wn * 32 + 16 + r16][lg * 8];                    \
        acc[0][0] = __builtin_amdgcn_mfma_f32_16x16x32_bf16(a0, b0, acc[0][0], 0, 0, 0);   \
        acc[0][1] = __builtin_amdgcn_mfma_f32_16x16x32_bf16(a0, b1, acc[0][1], 0, 0, 0);   \
        acc[1][0] = __builtin_amdgcn_mfma_f32_16x16x32_bf16(a1, b0, acc[1][0], 0, 0, 0);   \
        acc[1][1] = __builtin_amdgcn_mfma_f32_16x16x32_bf16(a1, b1, acc[1][1], 0, 0, 0);   \
    }

// ======================================================================
// offset conv
// ======================================================================
__global__ __launch_bounds__(512, 4) void off_mfma(const unsigned short* __restrict__ eT,
                                                   const unsigned short* __restrict__ wp,
                                                   const float* __restrict__ off_b,
                                                   float* __restrict__ om4) {
    __shared__ __align__(16) char sA[2][8192];
    __shared__ __align__(16) unsigned short sB[2][64][40];
    int bx = blockIdx.x;
    int b = bx >> 6, y = bx & 63;
    int ocbase = blockIdx.y * 128;
    int tid = threadIdx.x;
    int lane = tid & 63;
    int w = tid >> 6;
    int wu = __builtin_amdgcn_readfirstlane(w);
    int wm = w & 3, wn = w >> 2;
    int r16 = lane & 15, lg = lane >> 4;
    int swz = (r16 >> 1) & 3;
    int pxg = tid >> 3, grp = tid & 7;

    const unsigned short* eb = eT + (size_t)b * PH * PW * CC;

    f32x4 acc[2][2];
#pragma unroll
    for (int mi = 0; mi < 2; mi++)
#pragma unroll
        for (int ni = 0; ni < 2; ni++) acc[mi][ni] = (f32x4)0.f;

#define OF_STAGE(T, BN)                                                                         \
    {                                                                                           \
        int tap_ = (T) >> 3, cg_ = (T) & 7;                                                     \
        int ky_ = tap_ / 3, kx_ = tap_ - ky_ * 3;                                               \
        BN = *(const u32x2*)&eb[(size_t)((y + ky_ + 1) * PW + (pxg + kx_ + 1)) * CC + cg_ * 32 + \
                                grp * 4];                                                       \
    }
#define OF_IT(T, BUF)                                                        \
    {                                                                        \
        __syncthreads();                                                     \
        u32x2 bn;                                                            \
        if ((T) + 1 < NCHUNK) {                                              \
            GLDSA(wp, (T) + 1, (BUF) ^ 1);                                   \
            OF_STAGE((T) + 1, bn)                                            \
        }                                                                    \
        MFMA4(BUF)                                                           \
        if ((T) + 1 < NCHUNK) *(u32x2*)&sB[(BUF) ^ 1][pxg][grp * 4] = bn;    \
    }

    {
        GLDSA(wp, 0, 0);
        u32x2 b0v;
        OF_STAGE(0, b0v)
        *(u32x2*)&sB[0][pxg][grp * 4] = b0v;
    }
    for (int t = 0; t < NCHUNK; t += 2) {
        OF_IT(t, 0)
        OF_IT(t + 1, 1)
    }

    float* omb4 = om4 + (size_t)b * NCHUNK * HW * 4;
#pragma unroll
    for (int mi = 0; mi < 2; mi++) {
#pragma unroll
        for (int ni = 0; ni < 2; ni++) {
#pragma unroll
            for (int j = 0; j < 4; j++) {
                int oc = ocbase + wm * 32 + mi * 16 + lg * 4 + j;
                if (oc < OFFC) {
                    int pxo = wn * 32 + ni * 16 + r16;
                    float v = acc[mi][ni][j] + off_b[oc];
                    int dg, tap, comp;
                    if (oc < 144) {
                        dg = oc / 18;
                        int rr = oc - dg * 18;
                        tap = rr >> 1;
                        comp = rr & 1;
                    } else {
                        int o2 = oc - 144;
                        dg = o2 / 9;
                        tap = o2 - dg * 9;
                        comp = 2;
                    }
                    omb4[((size_t)(dg * 9 + tap) * HW + y * WW + pxo) * 4 + comp] = v;
                }
            }
        }
    }
}

// ======================================================================
// fused deformable sampling + main conv
// ======================================================================
__global__ __launch_bounds__(512, 4) void dconv_mfma(const unsigned short* __restrict__ xT,
                                                     const float* __restrict__ omP,
                                                     const unsigned short* __restrict__ wp,
                                                     const float* __restrict__ bias,
                                                     float* __restrict__ out) {
    __shared__ __align__(16) char sA[2][8192];
    __shared__ __align__(16) unsigned short sB[2][64][40];
    int bx = blockIdx.x;
    int b = bx >> 6, y = bx & 63;
    int ocbase = blockIdx.y * 128;
    int tid = threadIdx.x;
    int lane = tid & 63;
    int w = tid >> 6;
    int wu = __builtin_amdgcn_readfirstlane(w);
    int wm = w & 3, wn = w >> 2;
    int r16 = lane & 15, lg = lane >> 4;
    int swz = (r16 >> 1) & 3;
    int pxg = tid >> 3, grp = tid & 7;
    int yx = y * WW + pxg;

    const unsigned short* xb = xT + (size_t)b * PH * PW * CC;
    const float* omPb = omP + (size_t)b * NCHUNK * HW * 4;

    f32x4 acc[2][2];
#pragma unroll
    for (int mi = 0; mi < 2; mi++)
#pragma unroll
        for (int ni = 0; ni < 2; ni++) acc[mi][ni] = (f32x4)0.f;

#define DC_OML(T) (*(const u32x4*)(omPb + ((size_t)(T)*HW + yx) * 4))

#define DC_GATHER(T, OM, G00, G01, G10, G11)                                  \
    {                                                                         \
        int dg_ = ((T) * 57) >> 9;                                            \
        unsigned int iv_ = OM[0];                                             \
        int o00_ = (int)(iv_ & 8191u) << 8;                                   \
        int dxe_ = (int)((iv_ >> 13) & 1u) << 8;                              \
        int dye_ = ((iv_ >> 14) & 1u) ? (PW * CC) : 0;                        \
        const unsigned short* p_ = xb + dg_ * 32 + grp * 4;                   \
        G00 = *(const u32x2*)(p_ + o00_);                                     \
        G01 = *(const u32x2*)(p_ + o00_ + dxe_);                              \
        G10 = *(const u32x2*)(p_ + o00_ + dye_);                              \
        G11 = *(const u32x2*)(p_ + o00_ + dye_ + dxe_);                       \
    }
#define DC_FIN(OM, G00, G01, G10, G11, BUF)                                                        \
    {                                                                                              \
        float w00 = bflo(OM[1]), w01 = bfhi(OM[1]);                                                \
        float w10 = bflo(OM[2]), w11 = bfhi(OM[2]);                                                \
        float v0 = w00 * bflo(G00[0]) + w01 * bflo(G01[0]) + w10 * bflo(G10[0]) + w11 * bflo(G11[0]); \
        float v1 = w00 * bfhi(G00[0]) + w01 * bfhi(G01[0]) + w10 * bfhi(G10[0]) + w11 * bfhi(G11[0]); \
        float v2 = w00 * bflo(G00[1]) + w01 * bflo(G01[1]) + w10 * bflo(G10[1]) + w11 * bflo(G11[1]); \
        float v3 = w00 * bfhi(G00[1]) + w01 * bfhi(G01[1]) + w10 * bfhi(G10[1]) + w11 * bfhi(G11[1]); \
        u32x2 pk_;                                                                                 \
        pk_[0] = pkbf(v0, v1);                                                                     \
        pk_[1] = pkbf(v2, v3);                                                                     \
        *(u32x2*)&sB[BUF][pxg][grp * 4] = pk_;                                                     \
    }
#define DC_IT(T, BUF, OMC, OMN)                                               \
    {                                                                         \
        __syncthreads();                                                      \
        u32x2 g00, g01, g10, g11;                                             \
        if ((T) + 1 < NCHUNK) {                                               \
            GLDSA(wp, (T) + 1, (BUF) ^ 1);                                    \
            DC_GATHER((T) + 1, OMC, g00, g01, g10, g11)                       \
        }                                                                     \
        if ((T) + 2 < NCHUNK) OMN = DC_OML((T) + 2);                          \
        MFMA4(BUF)                                                            \
        if ((T) + 1 < NCHUNK) DC_FIN(OMC, g00, g01, g10, g11, (BUF) ^ 1)      \
    }

    u32x4 omC, omN;
    {
        GLDSA(wp, 0, 0);
        u32x4 om0 = DC_OML(0);
        u32x2 g00, g01, g10, g11;
        DC_GATHER(0, om0, g00, g01, g10, g11)
        DC_FIN(om0, g00, g01, g10, g11, 0)
    }
    omC = DC_OML(1);
    for (int t = 0; t < NCHUNK; t += 2) {
        DC_IT(t, 0, omC, omN)
        DC_IT(t + 1, 1, omN, omC)
    }

#pragma unroll
    for (int mi = 0; mi < 2; mi++) {
#pragma unroll
        for (int ni = 0; ni < 2; ni++) {
#pragma unroll
            for (int j = 0; j < 4; j++) {
                int oc = ocbase + wm * 32 + mi * 16 + lg * 4 + j;
                int pxo = wn * 32 + ni * 16 + r16;
                out[(size_t)(b * COUT + oc) * HW + y * WW + pxo] = acc[mi][ni][j] + bias[oc];
            }
        }
    }
}

extern "C" void kernel_launch(void* const* d_in, const int* in_sizes, int n_in,
                              void* d_out, int out_size, void* d_ws, size_t ws_size,
                              hipStream_t stream) {
    const float* x = (const float*)d_in[0];
    const float* extra_feat = (const float*)d_in[1];
    const float* weight = (const float*)d_in[2];
    const float* bias = (const float*)d_in[3];
    const float* off_w = (const float*)d_in[4];
    const float* off_b = (const float*)d_in[5];
    float* out = (float*)d_out;

    // workspace layout (same footprint as round 5, ~38.2 MB)
    float* omP = (float*)d_ws;                                      // 4*72*4096*4 f32 (raw -> processed in place)
    unsigned short* wpm = (unsigned short*)(omP + (size_t)BB * NCHUNK * HW * 4);
    unsigned short* wpo = wpm + (size_t)KTOT * COUT;
    unsigned short* xT = wpo + (size_t)KTOT * COUT;
    unsigned short* eT = xT + (size_t)BB * PH * PW * CC;

    pack_w_main<<<(KTOT * COUT) / 256, 256, 0, stream>>>(weight, wpm);
    pack_w_off<<<(KTOT * COUT) / 256, 256, 0, stream>>>(off_w, wpo);
    pad_tr2<<<dim3(BB * PH, 2), 256, 0, stream>>>(x, extra_feat, xT, eT);

    off_mfma<<<dim3(BB * HH, 2), 512, 0, stream>>>(eT, wpo, off_b, omP);
    prep_off<<<(BB * NCHUNK * HW) / 256, 256, 0, stream>>>(omP);
    dconv_mfma<<<dim3(BB * HH, 2), 512, 0, stream>>>(xT, omP, wpm, bias, out);
}